// Round 7
// baseline (1101.045 us; speedup 1.0000x reference)
//
#include <hip/hip_runtime.h>

#define NG 128   // num graphs
#define NL 4     // layers
#define ND 3     // dims

// ---------------- zero deg + pooled (kernel, not memset: capture-safe) ----------------
__global__ __launch_bounds__(256) void zero_kernel(
    int* __restrict__ deg, float* __restrict__ pooled, int N, int P) {
    int i = blockIdx.x * 256 + threadIdx.x;
    if (i < N) deg[i] = 0;
    if (i < P) pooled[i] = 0.f;
}

// ---------------- histogram dst degrees (int32 edge index!) ----------------
__global__ __launch_bounds__(256) void deg_hist_kernel(
    const int* __restrict__ eidx, int* __restrict__ deg, int E) {
    int e = blockIdx.x * 256 + threadIdx.x;
    if (e >= E) return;
    atomicAdd(&deg[eidx[E + e]], 1);
}

// ---------------- scan pass 1: per-block (1024 elems) sums ----------------
__global__ __launch_bounds__(256) void scan1_kernel(
    const int* __restrict__ deg, int* __restrict__ partial, int N) {
    __shared__ int sh[256];
    int t = threadIdx.x;
    int base = blockIdx.x * 1024 + t * 4;
    int ts = 0;
    #pragma unroll
    for (int j = 0; j < 4; j++) { int i = base + j; if (i < N) ts += deg[i]; }
    sh[t] = ts;
    __syncthreads();
    for (int off = 128; off > 0; off >>= 1) {
        if (t < off) sh[t] += sh[t + off];
        __syncthreads();
    }
    if (t == 0) partial[blockIdx.x] = sh[0];
}

// ---------------- scan pass 2: serial exclusive scan of partials (tiny) ----------------
__global__ void scan2_kernel(int* __restrict__ partial, int nb, int* __restrict__ rowptr, int N, int E) {
    if (threadIdx.x == 0) {
        int run = 0;
        for (int i = 0; i < nb; i++) { int v = partial[i]; partial[i] = run; run += v; }
        rowptr[N] = E;
    }
}

// ---------------- scan pass 3: block exclusive scan + offset -> rowptr, cursor ----------------
__global__ __launch_bounds__(256) void scan3_kernel(
    const int* __restrict__ deg, const int* __restrict__ partial,
    int* __restrict__ rowptr, int* __restrict__ cursor, int N) {
    __shared__ int sh[256];
    int t = threadIdx.x;
    int base = blockIdx.x * 1024 + t * 4;
    int d[4];
    #pragma unroll
    for (int j = 0; j < 4; j++) { int i = base + j; d[j] = (i < N) ? deg[i] : 0; }
    int ts = d[0] + d[1] + d[2] + d[3];
    sh[t] = ts;
    __syncthreads();
    for (int off = 1; off < 256; off <<= 1) {
        int v = (t >= off) ? sh[t - off] : 0;
        __syncthreads();
        sh[t] += v;
        __syncthreads();
    }
    int excl = sh[t] - ts + partial[blockIdx.x];
    int run = excl;
    #pragma unroll
    for (int j = 0; j < 4; j++) {
        int i = base + j;
        if (i < N) { rowptr[i] = run; cursor[i] = run; }
        run += d[j];
    }
}

// ---------------- fill CSR buckets: col[pos] = src (int32 eidx) ----------------
__global__ __launch_bounds__(256) void fill_kernel(
    const int* __restrict__ eidx,
    int* __restrict__ cursor, int* __restrict__ col, int E) {
    int e = blockIdx.x * 256 + threadIdx.x;
    if (e >= E) return;
    int s = eidx[e];
    int d = eidx[E + e];
    int pos = atomicAdd(&cursor[d], 1);
    col[pos] = s;
}

// ---------------- CSR gather aggregation: agg[i] = sum_{j in N(i)} h[j]  (no atomics) ----------------
// h compact N x 64. one wave per node; 4 edges/iter with float4 (16B/lane) loads:
//   lane = grp*16 + sub; grp = edge-in-batch (0..3), sub = feature quad (0..15)
__global__ __launch_bounds__(256) void agg_csr_kernel(
    const float* __restrict__ h, const int* __restrict__ rowptr,
    const int* __restrict__ col, float* __restrict__ agg, int N) {
    int node = blockIdx.x * 4 + (threadIdx.x >> 6);
    if (node >= N) return;
    int lane = threadIdx.x & 63;
    int grp = lane >> 4;
    int sub = lane & 15;
    int s = rowptr[node], e = rowptr[node + 1];
    float4 acc = make_float4(0.f, 0.f, 0.f, 0.f);
    int i = s;
    #pragma unroll 2
    for (; i + 4 <= e; i += 4) {
        int c = col[i + grp];
        const float4 v = *(const float4*)&h[(c << 6) + (sub << 2)];
        acc.x += v.x; acc.y += v.y; acc.z += v.z; acc.w += v.w;
    }
    if (i + grp < e) {
        int c = col[i + grp];
        const float4 v = *(const float4*)&h[(c << 6) + (sub << 2)];
        acc.x += v.x; acc.y += v.y; acc.z += v.z; acc.w += v.w;
    }
    acc.x += __shfl_xor(acc.x, 16, 64); acc.y += __shfl_xor(acc.y, 16, 64);
    acc.z += __shfl_xor(acc.z, 16, 64); acc.w += __shfl_xor(acc.w, 16, 64);
    acc.x += __shfl_xor(acc.x, 32, 64); acc.y += __shfl_xor(acc.y, 32, 64);
    acc.z += __shfl_xor(acc.z, 32, 64); acc.w += __shfl_xor(acc.w, 32, 64);
    if (grp == 0) *(float4*)&agg[(node << 6) + (sub << 2)] = acc;
}

// ---------------- fused GIN MLP + pooling contribution ----------------
// z = h+agg; z1 = relu(BN(z@W1+b1)); z2 = relu(BN(z1@W2+b2));
// hout = z2 (may alias hin: block-private rows, loads precede stores across barriers);
// pooled[dim][g][l64+c] += sum_rows z2[r][c]*x0[r][dim]  (segment-flush on sorted batch)
__global__ __launch_bounds__(256) void mlp_kernel(
    const float* hin, const float* __restrict__ agg,
    const float* __restrict__ x0, const int* __restrict__ batch,
    const float* __restrict__ W1, const float* __restrict__ b1,
    const float* __restrict__ g1, const float* __restrict__ be1,
    const float* __restrict__ W2, const float* __restrict__ b2,
    const float* __restrict__ g2, const float* __restrict__ be2,
    float* hout, float* __restrict__ pooled, int l64, int N) {
    __shared__ __align__(16) float zT[64][68];    // zT[c][r]; later reused row-major as zs[r*68+c]
    __shared__ __align__(16) float Wf[64][64];    // folded weights Wf[k][c] = W[k][c]*scale[c]
    __shared__ float sc[64], bcs[64];
    __shared__ float wsm[ND][64];                 // x0[row, dim] for this block's rows
    __shared__ int   sgr[64];                     // graph id per row
    const int t = threadIdx.x;
    const int r0 = blockIdx.x * 64;
    const float inv = rsqrtf(1.0f + 1e-5f);

    // ---- stage 1 constants ----
    if (t < 64) { float s = g1[t] * inv; sc[t] = s; bcs[t] = b1[t] * s + be1[t]; }
    __syncthreads();
    for (int i = t; i < 4096; i += 256) { int c = i & 63; Wf[i >> 6][c] = W1[i] * sc[c]; }
    // z = h + agg, stored transposed. lane: row rr = t>>2, col quad cq = (t&3)*4 (+16j)
    {
        const int rr = t >> 2;
        const int cq = (t & 3) << 2;
        const int row = r0 + rr;
        #pragma unroll
        for (int j = 0; j < 4; j++) {
            const int c = cq + j * 16;
            float4 v = make_float4(0.f, 0.f, 0.f, 0.f);
            if (row < N) {
                const float4 hv = *(const float4*)&hin[(row << 6) + c];
                const float4 av = *(const float4*)&agg[(row << 6) + c];
                v.x = hv.x + av.x; v.y = hv.y + av.y; v.z = hv.z + av.z; v.w = hv.w + av.w;
            }
            zT[c + 0][rr] = v.x; zT[c + 1][rr] = v.y; zT[c + 2][rr] = v.z; zT[c + 3][rr] = v.w;
        }
    }
    __syncthreads();

    const int ty = t & 15;   // rows 4ty..4ty+3
    const int tx = t >> 4;   // cols 4tx..4tx+3

    // ---- matmul 1 ----
    float acc[4][4];
    #pragma unroll
    for (int i = 0; i < 4; i++)
        #pragma unroll
        for (int j = 0; j < 4; j++) acc[i][j] = bcs[(tx << 2) + j];
    for (int k = 0; k < 64; k++) {
        const float4 zv = *(const float4*)&zT[k][ty << 2];
        const float4 wv = *(const float4*)&Wf[k][tx << 2];
        acc[0][0] = fmaf(zv.x, wv.x, acc[0][0]); acc[0][1] = fmaf(zv.x, wv.y, acc[0][1]);
        acc[0][2] = fmaf(zv.x, wv.z, acc[0][2]); acc[0][3] = fmaf(zv.x, wv.w, acc[0][3]);
        acc[1][0] = fmaf(zv.y, wv.x, acc[1][0]); acc[1][1] = fmaf(zv.y, wv.y, acc[1][1]);
        acc[1][2] = fmaf(zv.y, wv.z, acc[1][2]); acc[1][3] = fmaf(zv.y, wv.w, acc[1][3]);
        acc[2][0] = fmaf(zv.z, wv.x, acc[2][0]); acc[2][1] = fmaf(zv.z, wv.y, acc[2][1]);
        acc[2][2] = fmaf(zv.z, wv.z, acc[2][2]); acc[2][3] = fmaf(zv.z, wv.w, acc[2][3]);
        acc[3][0] = fmaf(zv.w, wv.x, acc[3][0]); acc[3][1] = fmaf(zv.w, wv.y, acc[3][1]);
        acc[3][2] = fmaf(zv.w, wv.z, acc[3][2]); acc[3][3] = fmaf(zv.w, wv.w, acc[3][3]);
    }
    __syncthreads();  // matmul1 reads done; safe to overwrite sc/Wf/zT

    // ---- stage 2 constants + pooling metadata ----
    if (t < 64) { float s = g2[t] * inv; sc[t] = s; bcs[t] = b2[t] * s + be2[t]; }
    if (t < 192) {  // wsm[dim][r] = x0[row, dim] (0 for rows >= N)
        int r = t & 63, d = t >> 6;
        int row = r0 + r;
        wsm[d][r] = (row < N) ? x0[(row << 6) + d] : 0.f;
    } else {        // sgr[r] = graph id (clamped row; weight 0 makes OOB rows harmless)
        int r = t - 192;
        int row = r0 + r; if (row >= N) row = N - 1;
        sgr[r] = batch[row];
    }
    __syncthreads();
    for (int i = t; i < 4096; i += 256) { int c = i & 63; Wf[i >> 6][c] = W2[i] * sc[c]; }
    // re-store relu(acc) transposed (4-way bank conflict, 16 instrs)
    #pragma unroll
    for (int j = 0; j < 4; j++) {
        float4 w;
        w.x = fmaxf(acc[0][j], 0.f); w.y = fmaxf(acc[1][j], 0.f);
        w.z = fmaxf(acc[2][j], 0.f); w.w = fmaxf(acc[3][j], 0.f);
        *(float4*)&zT[(tx << 2) + j][ty << 2] = w;
    }
    __syncthreads();

    // ---- matmul 2 ----
    float acc2[4][4];
    #pragma unroll
    for (int i = 0; i < 4; i++)
        #pragma unroll
        for (int j = 0; j < 4; j++) acc2[i][j] = bcs[(tx << 2) + j];
    for (int k = 0; k < 64; k++) {
        const float4 zv = *(const float4*)&zT[k][ty << 2];
        const float4 wv = *(const float4*)&Wf[k][tx << 2];
        acc2[0][0] = fmaf(zv.x, wv.x, acc2[0][0]); acc2[0][1] = fmaf(zv.x, wv.y, acc2[0][1]);
        acc2[0][2] = fmaf(zv.x, wv.z, acc2[0][2]); acc2[0][3] = fmaf(zv.x, wv.w, acc2[0][3]);
        acc2[1][0] = fmaf(zv.y, wv.x, acc2[1][0]); acc2[1][1] = fmaf(zv.y, wv.y, acc2[1][1]);
        acc2[1][2] = fmaf(zv.y, wv.z, acc2[1][2]); acc2[1][3] = fmaf(zv.y, wv.w, acc2[1][3]);
        acc2[2][0] = fmaf(zv.z, wv.x, acc2[2][0]); acc2[2][1] = fmaf(zv.z, wv.y, acc2[2][1]);
        acc2[2][2] = fmaf(zv.z, wv.z, acc2[2][2]); acc2[2][3] = fmaf(zv.z, wv.w, acc2[2][3]);
        acc2[3][0] = fmaf(zv.w, wv.x, acc2[3][0]); acc2[3][1] = fmaf(zv.w, wv.y, acc2[3][1]);
        acc2[3][2] = fmaf(zv.w, wv.z, acc2[3][2]); acc2[3][3] = fmaf(zv.w, wv.w, acc2[3][3]);
    }
    __syncthreads();  // matmul2 zT reads done; zT reusable row-major

    // ---- epilogue: relu; write compact h_next (may alias hin); stash zs in LDS ----
    float* zsf = &zT[0][0];   // zs[r][c] at zsf[r*68+c]
    #pragma unroll
    for (int i = 0; i < 4; i++) {
        const int r = (ty << 2) + i;
        const int row = r0 + r;
        float4 o;
        o.x = fmaxf(acc2[i][0], 0.f); o.y = fmaxf(acc2[i][1], 0.f);
        o.z = fmaxf(acc2[i][2], 0.f); o.w = fmaxf(acc2[i][3], 0.f);
        if (hout && row < N) *(float4*)&hout[(row << 6) + (tx << 2)] = o;
        *(float4*)&zsf[r * 68 + (tx << 2)] = o;
    }
    __syncthreads();

    // ---- pooling: per-strip (16 rows) weighted column sums, segment-flush on sorted batch ----
    {
        const int c = t & 63;
        const int strip = t >> 6;           // wave-uniform
        float a0 = 0.f, a1 = 0.f, a2 = 0.f;
        int curg = sgr[strip * 16];
        #pragma unroll
        for (int rr = 0; rr < 16; rr++) {
            const int r = strip * 16 + rr;
            const int g = sgr[r];           // wave-uniform
            if (g != curg) {
                atomicAdd(&pooled[(0 * NG + curg) * 256 + l64 + c], a0);
                atomicAdd(&pooled[(1 * NG + curg) * 256 + l64 + c], a1);
                atomicAdd(&pooled[(2 * NG + curg) * 256 + l64 + c], a2);
                a0 = a1 = a2 = 0.f; curg = g;
            }
            const float v = zsf[r * 68 + c];
            a0 = fmaf(v, wsm[0][r], a0);
            a1 = fmaf(v, wsm[1][r], a1);
            a2 = fmaf(v, wsm[2][r], a2);
        }
        atomicAdd(&pooled[(0 * NG + curg) * 256 + l64 + c], a0);
        atomicAdd(&pooled[(1 * NG + curg) * 256 + l64 + c], a1);
        atomicAdd(&pooled[(2 * NG + curg) * 256 + l64 + c], a2);
    }
}

// ---------------- readout: out = (sum_dim relu(pooled@Wd+bd)) @ Wout + bout ----------------
__global__ __launch_bounds__(64) void readout_kernel(
    const float* __restrict__ pooled, const float* __restrict__ Wd, const float* __restrict__ bd,
    const float* __restrict__ Wout, const float* __restrict__ bout,
    float* __restrict__ out, int C) {
    int g = blockIdx.x, c = threadIdx.x;  // 64 threads
    __shared__ float sh[64];
    float v = 0.f;
    for (int dim = 0; dim < ND; dim++) {
        float acc = bd[dim * 64 + c];
        const float* p = pooled + dim * NG * 256 + g * 256;
        const float* wmat = Wd + dim * 256 * 64;
        for (int k = 0; k < 256; k++) acc = fmaf(p[k], wmat[k * 64 + c], acc);
        v += fmaxf(acc, 0.f);
    }
    sh[c] = v;
    __syncthreads();
    if (c < C) {
        float acc = bout[c];
        #pragma unroll
        for (int k = 0; k < 64; k++) acc = fmaf(sh[k], Wout[k * C + c], acc);
        out[g * C + c] = acc;
    }
}

extern "C" void kernel_launch(void* const* d_in, const int* in_sizes, int n_in,
                              void* d_out, int out_size, void* d_ws, size_t ws_size,
                              hipStream_t stream) {
    const float* x     = (const float*)d_in[0];
    const int*   eidx  = (const int*)d_in[1];   // int32! (jax default x64-disabled)
    const int*   batch = (const int*)d_in[2];   // int32!
    const float* W1  = (const float*)d_in[3];
    const float* b1  = (const float*)d_in[4];
    const float* g1  = (const float*)d_in[5];
    const float* be1 = (const float*)d_in[6];
    const float* W2  = (const float*)d_in[7];
    const float* b2  = (const float*)d_in[8];
    const float* g2  = (const float*)d_in[9];
    const float* be2 = (const float*)d_in[10];
    const float* Wd  = (const float*)d_in[11];
    const float* bd  = (const float*)d_in[12];
    const float* Wo  = (const float*)d_in[13];
    const float* bo  = (const float*)d_in[14];

    const int N = in_sizes[0] / 64;
    const int E = in_sizes[1] / 2;
    const int C = in_sizes[14];
    const int P = ND * NG * 256;

    // workspace layout (~66 MB)
    float* ws     = (float*)d_ws;
    float* agg    = ws;                          // N*64 floats
    float* hA     = agg + (size_t)N * 64;        // N*64 floats
    float* pooled = hA + (size_t)N * 64;         // P floats
    int*   ibase  = (int*)(pooled + P);
    int* col    = ibase;               // E
    int* deg    = col + E;             // N
    int* rowptr = deg + N;             // N+1
    int* cursor = rowptr + N + 1;      // N
    int* partial= cursor + N;          // 128

    // ws guard: if scratch too small, skip all work (distinguishes overflow from crash)
    size_t need = ((size_t)N * 128 + P) * 4 + ((size_t)E + 3 * (size_t)N + 129) * 4;
    if (ws_size < need) return;

    const int nb = (N + 1023) / 1024;  // scan blocks (needs partial[] >= nb; nb<=128 for N<=131072)

    // ---- CSR build (once per call; reused by all 4 layers) ----
    {
        int zn = (N > P ? N : P);
        zero_kernel<<<(zn + 255) / 256, 256, 0, stream>>>(deg, pooled, N, P);
    }
    deg_hist_kernel<<<(E + 255) / 256, 256, 0, stream>>>(eidx, deg, E);
    scan1_kernel<<<nb, 256, 0, stream>>>(deg, partial, N);
    scan2_kernel<<<1, 64, 0, stream>>>(partial, nb, rowptr, N, E);
    scan3_kernel<<<nb, 256, 0, stream>>>(deg, partial, rowptr, cursor, N);
    fill_kernel<<<(E + 255) / 256, 256, 0, stream>>>(eidx, cursor, col, E);

    // ---- layers: h chain x -> hA -> hA (in-place) -> hA -> (none) ----
    const int mblocks = (N + 63) / 64;
    for (int l = 0; l < NL; l++) {
        const float* hin = (l == 0) ? x : hA;
        float*       hout = (l == NL - 1) ? nullptr : hA;
        agg_csr_kernel<<<(N + 3) / 4, 256, 0, stream>>>(hin, rowptr, col, agg, N);
        mlp_kernel<<<mblocks, 256, 0, stream>>>(
            hin, agg, x, batch,
            W1 + (size_t)l * 4096, b1 + l * 64, g1 + l * 64, be1 + l * 64,
            W2 + (size_t)l * 4096, b2 + l * 64, g2 + l * 64, be2 + l * 64,
            hout, pooled, l * 64, N);
    }

    // ---- readout ----
    readout_kernel<<<NG, 64, 0, stream>>>(pooled, Wd, bd, Wo, bo, (float*)d_out, C);
}